// Round 10
// baseline (52.913 us; speedup 1.0000x reference)
//
#include <hip/hip_runtime.h>
#include <math.h>

// MorphLayer via max-product identity (exp monotone, exp∘log∘clamp = clamp):
//   exp(max_k(log(max(±x,eps)) + w_k)) = max_k( max(±x,eps) * exp(w_k) )
// R10: MEASUREMENT ROUND. Inner tap-compute repeated REP=8 times with asm
// opacity barriers (same final output: max over identical passes). Purpose:
// dur = REP*c + f -> solve for inner-compute time c vs fixed floor f using
// R9's (c + f = 14.7us). Also promotes morph above the 38us poison fills in
// rocprof top-5 so steady-state VALUBusy/Occupancy finally become visible.

#define BB 16
#define CC 3
#define HH 66
#define WW 66
#define HO 64
#define WO 64
#define FF 32
#define KK 27
#define FPB 4               // filters per block (1 per wave)
#define FG (FF / FPB)       // 8 filter groups
#define ROWS 4              // output rows per block
#define IR (ROWS + 2)       // staged input rows = 6
#define LP 68               // padded LDS row length
#define WSTRIDE 56          // padded per-wave weight block (floats)
#define REP 8               // inner-compute repetitions (measurement)

typedef float f32x2 __attribute__((ext_vector_type(2)));
typedef float f32x4 __attribute__((ext_vector_type(4)));

__global__ __launch_bounds__(256, 8)
void morph_tile(const float* __restrict__ x,
                const float* __restrict__ k1,
                const float* __restrict__ k2,
                const float* __restrict__ bias,
                float* __restrict__ out) {
    __shared__ __align__(16) float xs[CC * IR * LP];       // 4896 B
    __shared__ __align__(16) float wl[FPB * WSTRIDE];      // 896 B

    const int tid = threadIdx.x;
    int bid = blockIdx.x;
    const int fg = bid & (FG - 1); bid >>= 3;
    const int rb = bid & 15;       bid >>= 4;
    const int b  = bid;
    const int f0 = fg * FPB;
    const int ho0 = rb * ROWS;

    if (tid < FPB * KK * 2) {
        const int w_  = tid / (KK * 2);
        const int rem = tid - w_ * (KK * 2);
        const int k   = rem >> 1;
        const int h   = rem & 1;
        const float wv = h ? k2[k * FF + f0 + w_] : k1[k * FF + f0 + w_];
        wl[w_ * WSTRIDE + k * 2 + h] = expf(wv);
    }
    const float* xbase = x + (size_t)b * CC * HH * WW;
    for (int i = tid; i < CC * IR * WW; i += 256) {
        const int c   = i / (IR * WW);
        const int rem = i - c * (IR * WW);
        const int row = rem / WW;
        const int col = rem - row * WW;
        xs[(c * IR + row) * LP + col] = xbase[(c * HH + ho0 + row) * WW + col];
    }
    __syncthreads();

    const int w   = tid >> 6;
    const int l   = tid & 63;
    const int rr  = l >> 4;
    const int wo4 = (l & 15) * 4;

    const float* wlw = wl + w * WSTRIDE;
    const int f = f0 + w;

    float m11_0 = 0.f, m11_1 = 0.f, m11_2 = 0.f, m11_3 = 0.f;
    float m12_0 = 0.f, m12_1 = 0.f, m12_2 = 0.f, m12_3 = 0.f;
    float m21_0 = 0.f, m21_1 = 0.f, m21_2 = 0.f, m21_3 = 0.f;
    float m22_0 = 0.f, m22_1 = 0.f, m22_2 = 0.f, m22_3 = 0.f;

#define TAP(k, va, vb, vc, vd) { \
        const f32x2 e = *(const f32x2*)(wlw + (k) * 2); \
        const f32x2 ab = {va, vb}, cd = {vc, vd}; \
        const f32x2 e1 = {e.x, e.x}, e2 = {e.y, e.y}; \
        const f32x2 p1 = ab * e1, q1 = cd * e1; \
        const f32x2 p2 = ab * e2, q2 = cd * e2; \
        m11_0 = fmaxf(m11_0,  p1.x); m11_1 = fmaxf(m11_1,  p1.y); \
        m11_2 = fmaxf(m11_2,  q1.x); m11_3 = fmaxf(m11_3,  q1.y); \
        m12_0 = fmaxf(m12_0,  p2.x); m12_1 = fmaxf(m12_1,  p2.y); \
        m12_2 = fmaxf(m12_2,  q2.x); m12_3 = fmaxf(m12_3,  q2.y); \
        m21_0 = fmaxf(m21_0, -p1.x); m21_1 = fmaxf(m21_1, -p1.y); \
        m21_2 = fmaxf(m21_2, -q1.x); m21_3 = fmaxf(m21_3, -q1.y); \
        m22_0 = fmaxf(m22_0, -p2.x); m22_1 = fmaxf(m22_1, -p2.y); \
        m22_2 = fmaxf(m22_2, -q2.x); m22_3 = fmaxf(m22_3, -q2.y); \
    }

    // Loaded x values pass through an asm barrier -> compiler cannot CSE or
    // hoist across rep iterations; each rep re-reads LDS and re-computes.
#define CHUNK(c, di) { \
        const int base_ = ((c * IR + rr + (di)) * LP + wo4); \
        f32x4 xq = *(const f32x4*)(xs + base_); \
        f32x2 xr = *(const f32x2*)(xs + base_ + 4); \
        float s0 = xq.x, s1 = xq.y, s2 = xq.z, s3 = xq.w; \
        float s4 = xr.x, s5 = xr.y; \
        asm volatile("" : "+v"(s0), "+v"(s1), "+v"(s2), "+v"(s3), \
                          "+v"(s4), "+v"(s5)); \
        TAP((c) * 9 + (di) * 3 + 0, s0, s1, s2, s3) \
        TAP((c) * 9 + (di) * 3 + 1, s1, s2, s3, s4) \
        TAP((c) * 9 + (di) * 3 + 2, s2, s3, s4, s5) \
    }

    #pragma unroll 1
    for (int rep = 0; rep < REP; ++rep) {
        CHUNK(0, 0) CHUNK(0, 1) CHUNK(0, 2)
        CHUNK(1, 0) CHUNK(1, 1) CHUNK(1, 2)
        CHUNK(2, 0) CHUNK(2, 1) CHUNK(2, 2)
    }
#undef CHUNK
#undef TAP

    const float bs = bias[f];
    f32x4 res;
    res.x = m11_0 - m12_0 - m21_0 + m22_0 + bs;
    res.y = m11_1 - m12_1 - m21_1 + m22_1 + bs;
    res.z = m11_2 - m12_2 - m21_2 + m22_2 + bs;
    res.w = m11_3 - m12_3 - m21_3 + m22_3 + bs;

    *(f32x4*)(out + (((size_t)b * FF + f) * HO + ho0 + rr) * WO + wo4) = res;
}

extern "C" void kernel_launch(void* const* d_in, const int* in_sizes, int n_in,
                              void* d_out, int out_size, void* d_ws, size_t ws_size,
                              hipStream_t stream) {
    const float* x    = (const float*)d_in[0];
    const float* k1   = (const float*)d_in[1];
    const float* k2   = (const float*)d_in[2];
    const float* bias = (const float*)d_in[3];
    float* out = (float*)d_out;

    const int nblocks = BB * (HO / ROWS) * FG;  // 2048
    morph_tile<<<dim3(nblocks), dim3(256), 0, stream>>>(x, k1, k2, bias, out);
}

// Round 11
// 14.478 us; speedup vs baseline: 3.6547x; 3.6547x over previous
//
#include <hip/hip_runtime.h>
#include <math.h>

// MorphLayer via max-product identity (exp monotone, exp∘log∘clamp = clamp):
//   exp(max_k(log(max(±x,eps)) + w_k)) = max_k( max(±x,eps) * exp(w_k) )
// Negation identity: max(-v,e)*w = max(-(v*w), e*w); eps-term ~1e-12 -> init 0.
// R11: compress inner compute c (R10 measured c=5.5us, f=9.2us):
//  - max3 tap-pairing: 2 max-reductions per issue (v_max3_f32, free -mods)
//  - 8 outputs/thread (2 rows x 4 cols): window rows in registers, 9 taps/chan
//    served by one 8xb128 load block; LDS pipe drops under VALU
//  - all-b128 aligned LDS reads -> bank-conflict-free per 16-lane phase

#define BB 16
#define CC 3
#define HH 66
#define WW 66
#define HO 64
#define WO 64
#define FF 32
#define KK 27
#define FPB 4               // filters per block (1 per wave)
#define FG (FF / FPB)       // 8 filter groups
#define OROWS 8             // output rows per block (2 per thread)
#define IR (OROWS + 2)      // staged input rows = 10
#define LP 68               // padded LDS row length (16B-aligned b128)
#define WSTRIDE 56          // per-wave weight block stride (floats)

typedef float f32x2 __attribute__((ext_vector_type(2)));
typedef float f32x4 __attribute__((ext_vector_type(4)));

__global__ __launch_bounds__(256, 4)
void morph_tile(const float* __restrict__ x,
                const float* __restrict__ k1,
                const float* __restrict__ k2,
                const float* __restrict__ bias,
                float* __restrict__ out) {
    __shared__ __align__(16) float xs[CC * IR * LP];    // 8160 B
    __shared__ __align__(16) float wl[FPB * WSTRIDE];   // 896 B

    const int tid = threadIdx.x;
    int bid = blockIdx.x;
    const int fg = bid & (FG - 1); bid >>= 3;   // filter group 0..7
    const int rb = bid & 7;        bid >>= 3;   // row band 0..7 (8 rows each)
    const int b  = bid;                         // batch
    const int f0 = fg * FPB;
    const int ho0 = rb * OROWS;

    // ---- per-wave weights: wl[w*WSTRIDE + k*2 + h] = exp((h?k2:k1)[k][f0+w]) ----
    if (tid < FPB * KK * 2) {
        const int w_  = tid / (KK * 2);
        const int rem = tid - w_ * (KK * 2);
        const int k   = rem >> 1;
        const int h   = rem & 1;
        const float wv = h ? k2[k * FF + f0 + w_] : k1[k * FF + f0 + w_];
        wl[w_ * WSTRIDE + k * 2 + h] = expf(wv);
    }
    // ---- stage x window (rows ho0..ho0+9, 3 channels), padded rows ----
    const float* xbase = x + (size_t)b * CC * HH * WW;
    for (int i = tid; i < CC * IR * WW; i += 256) {
        const int c   = i / (IR * WW);
        const int rem = i - c * (IR * WW);
        const int row = rem / WW;
        const int col = rem - row * WW;
        xs[(c * IR + row) * LP + col] = xbase[(c * HH + ho0 + row) * WW + col];
    }
    __syncthreads();

    const int w   = tid >> 6;          // wave = filter index within group
    const int l   = tid & 63;
    const int rq  = l >> 4;            // row-pair 0..3
    const int wo4 = (l & 15) * 4;      // first output col
    const int r0  = rq * 2;            // first output row (block-local)

    const float* wlw = wl + w * WSTRIDE;
    const int f = f0 + w;

    // 32 accumulators: [row-half h][col j], 4 chains each
    float m11[2][4], m12[2][4], m21[2][4], m22[2][4];
    #pragma unroll
    for (int h = 0; h < 2; ++h)
        #pragma unroll
        for (int j = 0; j < 4; ++j) {
            m11[h][j] = 0.f; m12[h][j] = 0.f; m21[h][j] = 0.f; m22[h][j] = 0.f;
        }

    // register window: 4 rows x 8 cols (cols wo4..wo4+7), all indices literal
    float xw[4][8];

#define LOADCH(c) { \
        const float* xc_ = xs + ((c) * IR + r0) * LP + wo4; \
        *(f32x4*)&xw[0][0] = *(const f32x4*)(xc_); \
        *(f32x4*)&xw[0][4] = *(const f32x4*)(xc_ + 4); \
        *(f32x4*)&xw[1][0] = *(const f32x4*)(xc_ + LP); \
        *(f32x4*)&xw[1][4] = *(const f32x4*)(xc_ + LP + 4); \
        *(f32x4*)&xw[2][0] = *(const f32x4*)(xc_ + 2 * LP); \
        *(f32x4*)&xw[2][4] = *(const f32x4*)(xc_ + 2 * LP + 4); \
        *(f32x4*)&xw[3][0] = *(const f32x4*)(xc_ + 3 * LP); \
        *(f32x4*)&xw[3][4] = *(const f32x4*)(xc_ + 3 * LP + 4); \
    }

    // one row-half of a tap PAIR: 8 pk_mul + 16 max3 (fmax(fmax) fuses; -mods free)
#define TP_H(h, Ai, Aj, Bi, Bj, e1A, e2A, e1B, e2B) { \
        const f32x2 pA1 = (f32x2){xw[(Ai)+(h)][(Aj)],   xw[(Ai)+(h)][(Aj)+1]} * e1A; \
        const f32x2 qA1 = (f32x2){xw[(Ai)+(h)][(Aj)+2], xw[(Ai)+(h)][(Aj)+3]} * e1A; \
        const f32x2 pA2 = (f32x2){xw[(Ai)+(h)][(Aj)],   xw[(Ai)+(h)][(Aj)+1]} * e2A; \
        const f32x2 qA2 = (f32x2){xw[(Ai)+(h)][(Aj)+2], xw[(Ai)+(h)][(Aj)+3]} * e2A; \
        const f32x2 pB1 = (f32x2){xw[(Bi)+(h)][(Bj)],   xw[(Bi)+(h)][(Bj)+1]} * e1B; \
        const f32x2 qB1 = (f32x2){xw[(Bi)+(h)][(Bj)+2], xw[(Bi)+(h)][(Bj)+3]} * e1B; \
        const f32x2 pB2 = (f32x2){xw[(Bi)+(h)][(Bj)],   xw[(Bi)+(h)][(Bj)+1]} * e2B; \
        const f32x2 qB2 = (f32x2){xw[(Bi)+(h)][(Bj)+2], xw[(Bi)+(h)][(Bj)+3]} * e2B; \
        m11[h][0] = fmaxf(fmaxf(m11[h][0],  pA1.x),  pB1.x); \
        m11[h][1] = fmaxf(fmaxf(m11[h][1],  pA1.y),  pB1.y); \
        m11[h][2] = fmaxf(fmaxf(m11[h][2],  qA1.x),  qB1.x); \
        m11[h][3] = fmaxf(fmaxf(m11[h][3],  qA1.y),  qB1.y); \
        m12[h][0] = fmaxf(fmaxf(m12[h][0],  pA2.x),  pB2.x); \
        m12[h][1] = fmaxf(fmaxf(m12[h][1],  pA2.y),  pB2.y); \
        m12[h][2] = fmaxf(fmaxf(m12[h][2],  qA2.x),  qB2.x); \
        m12[h][3] = fmaxf(fmaxf(m12[h][3],  qA2.y),  qB2.y); \
        m21[h][0] = fmaxf(fmaxf(m21[h][0], -pA1.x), -pB1.x); \
        m21[h][1] = fmaxf(fmaxf(m21[h][1], -pA1.y), -pB1.y); \
        m21[h][2] = fmaxf(fmaxf(m21[h][2], -qA1.x), -qB1.x); \
        m21[h][3] = fmaxf(fmaxf(m21[h][3], -qA1.y), -qB1.y); \
        m22[h][0] = fmaxf(fmaxf(m22[h][0], -pA2.x), -pB2.x); \
        m22[h][1] = fmaxf(fmaxf(m22[h][1], -pA2.y), -pB2.y); \
        m22[h][2] = fmaxf(fmaxf(m22[h][2], -qA2.x), -qB2.x); \
        m22[h][3] = fmaxf(fmaxf(m22[h][3], -qA2.y), -qB2.y); \
    }

#define TAPPAIR(Ai, Aj, Bi, Bj, kA, kB) { \
        const f32x2 eA_ = *(const f32x2*)(wlw + (kA) * 2); \
        const f32x2 eB_ = *(const f32x2*)(wlw + (kB) * 2); \
        const f32x2 e1A = {eA_.x, eA_.x}, e2A = {eA_.y, eA_.y}; \
        const f32x2 e1B = {eB_.x, eB_.x}, e2B = {eB_.y, eB_.y}; \
        TP_H(0, Ai, Aj, Bi, Bj, e1A, e2A, e1B, e2B) \
        TP_H(1, Ai, Aj, Bi, Bj, e1A, e2A, e1B, e2B) \
    }

    // single tap (channel tail): per h, 4 pk_mul + 16 fmax
#define TS_H(h, Ai, Aj, e1A, e2A) { \
        const f32x2 p1 = (f32x2){xw[(Ai)+(h)][(Aj)],   xw[(Ai)+(h)][(Aj)+1]} * e1A; \
        const f32x2 q1 = (f32x2){xw[(Ai)+(h)][(Aj)+2], xw[(Ai)+(h)][(Aj)+3]} * e1A; \
        const f32x2 p2 = (f32x2){xw[(Ai)+(h)][(Aj)],   xw[(Ai)+(h)][(Aj)+1]} * e2A; \
        const f32x2 q2 = (f32x2){xw[(Ai)+(h)][(Aj)+2], xw[(Ai)+(h)][(Aj)+3]} * e2A; \
        m11[h][0] = fmaxf(m11[h][0],  p1.x); m11[h][1] = fmaxf(m11[h][1],  p1.y); \
        m11[h][2] = fmaxf(m11[h][2],  q1.x); m11[h][3] = fmaxf(m11[h][3],  q1.y); \
        m12[h][0] = fmaxf(m12[h][0],  p2.x); m12[h][1] = fmaxf(m12[h][1],  p2.y); \
        m12[h][2] = fmaxf(m12[h][2],  q2.x); m12[h][3] = fmaxf(m12[h][3],  q2.y); \
        m21[h][0] = fmaxf(m21[h][0], -p1.x); m21[h][1] = fmaxf(m21[h][1], -p1.y); \
        m21[h][2] = fmaxf(m21[h][2], -q1.x); m21[h][3] = fmaxf(m21[h][3], -q1.y); \
        m22[h][0] = fmaxf(m22[h][0], -p2.x); m22[h][1] = fmaxf(m22[h][1], -p2.y); \
        m22[h][2] = fmaxf(m22[h][2], -q2.x); m22[h][3] = fmaxf(m22[h][3], -q2.y); \
    }

#define TAPSINGLE(Ai, Aj, kA) { \
        const f32x2 eA_ = *(const f32x2*)(wlw + (kA) * 2); \
        const f32x2 e1A = {eA_.x, eA_.x}, e2A = {eA_.y, eA_.y}; \
        TS_H(0, Ai, Aj, e1A, e2A) \
        TS_H(1, Ai, Aj, e1A, e2A) \
    }

    // channel c: taps k = c*9 + di*3 + dj; window rows xw[di+h], cols dj..dj+3
#define CHANNEL(c) { \
        LOADCH(c) \
        TAPPAIR(0, 0, 0, 1, (c)*9 + 0, (c)*9 + 1) \
        TAPPAIR(0, 2, 1, 0, (c)*9 + 2, (c)*9 + 3) \
        TAPPAIR(1, 1, 1, 2, (c)*9 + 4, (c)*9 + 5) \
        TAPPAIR(2, 0, 2, 1, (c)*9 + 6, (c)*9 + 7) \
        TAPSINGLE(2, 2, (c)*9 + 8) \
    }

    CHANNEL(0)
    CHANNEL(1)
    CHANNEL(2)

#undef CHANNEL
#undef TAPSINGLE
#undef TS_H
#undef TAPPAIR
#undef TP_H
#undef LOADCH

    const float bs = bias[f];
    #pragma unroll
    for (int h = 0; h < 2; ++h) {
        f32x4 res;
        res.x = m11[h][0] - m12[h][0] - m21[h][0] + m22[h][0] + bs;
        res.y = m11[h][1] - m12[h][1] - m21[h][1] + m22[h][1] + bs;
        res.z = m11[h][2] - m12[h][2] - m21[h][2] + m22[h][2] + bs;
        res.w = m11[h][3] - m12[h][3] - m21[h][3] + m22[h][3] + bs;
        *(f32x4*)(out + (((size_t)b * FF + f) * HO + ho0 + r0 + h) * WO + wo4) = res;
    }
}

extern "C" void kernel_launch(void* const* d_in, const int* in_sizes, int n_in,
                              void* d_out, int out_size, void* d_ws, size_t ws_size,
                              hipStream_t stream) {
    const float* x    = (const float*)d_in[0];
    const float* k1   = (const float*)d_in[1];
    const float* k2   = (const float*)d_in[2];
    const float* bias = (const float*)d_in[3];
    float* out = (float*)d_out;

    const int nblocks = BB * (HO / OROWS) * FG;  // 16 * 8 * 8 = 1024
    morph_tile<<<dim3(nblocks), dim3(256), 0, stream>>>(x, k1, k2, bias, out);
}